// Round 14
// baseline (1914.467 us; speedup 1.0000x reference)
//
#include <hip/hip_runtime.h>
#include <hip/hip_fp16.h>

#define B_  32
#define T_  2048
#define I_  256
#define H_  128
#define CH_ 16
#define NCH (T_ / CH_)

typedef _Float16 f16;
typedef _Float16 f16x2 __attribute__((ext_vector_type(2)));
typedef _Float16 f16x4 __attribute__((ext_vector_type(4)));
typedef _Float16 f16x8 __attribute__((ext_vector_type(8)));
typedef float    f32x4 __attribute__((ext_vector_type(4)));

#if __has_builtin(__builtin_amdgcn_fdot2)
#define FDOT2(a, b, c) __builtin_amdgcn_fdot2((a), (b), (c), false)
#else
static __device__ __forceinline__ float FDOT2(f16x2 a, f16x2 b, float c) {
  return c + (float)a[0] * (float)b[0] + (float)a[1] * (float)b[1];
}
#endif

static __device__ __forceinline__ f16x2 asf16x2(unsigned u) {
  return __builtin_bit_cast(f16x2, u);
}

//   xor1: [1,0,3,2]=0xB1   xor2: [2,3,0,1]=0x4E   xor3: [3,2,1,0]=0x1B
#define DPPF(x, ctrl)                                                      \
  __builtin_bit_cast(float, __builtin_amdgcn_mov_dpp(                      \
      __builtin_bit_cast(int, (x)), (ctrl), 0xF, 0xF, true))

static __device__ __forceinline__ float fast_sig(float x) {
  float e = __builtin_amdgcn_exp2f(-1.44269504089f * x);
  return __builtin_amdgcn_rcpf(1.0f + e);
}
static __device__ __forceinline__ float fast_tanh(float x) {
  float e = __builtin_amdgcn_exp2f(-2.88539008178f * x);
  return 2.0f * __builtin_amdgcn_rcpf(1.0f + e) - 1.0f;
}

#define BARRIER_LDS()                                   \
  __builtin_amdgcn_sched_barrier(0);                    \
  asm volatile("s_waitcnt lgkmcnt(0)" ::: "memory");    \
  __builtin_amdgcn_s_barrier();                         \
  __builtin_amdgcn_sched_barrier(0)

#define MFMA16(a, b, c) __builtin_amdgcn_mfma_f32_16x16x32_f16((a), (b), (c), 0, 0, 0)

// ---------------------------------------------------------------------------
// Prep: W_ih (f32, row = gate*128+unit) -> f16, PERMUTED row = unit*4+gate,
//   both dirs.  wih16[dir*512 + unit*4+gate][k].
// ---------------------------------------------------------------------------
__global__ __launch_bounds__(64) void wprep(
    const float* __restrict__ Wf_ih, const float* __restrict__ Wb_ih,
    f16* __restrict__ wih16)
{
  int row = blockIdx.x;                 // 0..1023
  int d = row >> 9, col = row & 511;
  int unit = col >> 2, gate = col & 3;
  const float* src = (d ? Wb_ih : Wf_ih) + (size_t)(gate * 128 + unit) * I_;
  int t = threadIdx.x;                  // 0..63
  float4 v = *(const float4*)&src[t * 4];
  f16x4 h = { (f16)v.x, (f16)v.y, (f16)v.z, (f16)v.w };
  *(f16x4*)&wih16[(size_t)row * I_ + t * 4] = h;
}

// ---------------------------------------------------------------------------
// Fused BiLSTM: 64 WGs x 512 thr (8 waves), one (dir,b) chain per WG.
// Consumer = R11 structure (VALU dots, DPP reduce, 1 LDS barrier/step).
// Producer = in-kernel xg GEMM on the idle MFMA pipe, 2 chunks ahead:
//   per chunk (16 steps): steps 0-7 accumulate D=(x16x256)·(W_ih^T 64-col
//   slice/wave) with 4 MFMA + 1 LDS A-frag + 4 global B-frags per step;
//   steps 8-15 store 2 f16 gate values each into a 64-slot ring in ws
//   (4 MB total -> L2-resident).  x rows (flip applied here) are staged to
//   LDS one chunk ahead (float4 loads at s=4, ds_write at s=14).
//   Per-chunk vmcnt(0)+barrier publishes ring stores; first consumer
//   prefetch of that chunk is >=1 chunk later (slot distance 32 mod 64).
// ---------------------------------------------------------------------------
__global__ __launch_bounds__(512, 1) void birnn_fused(
    const float* __restrict__ x, const f16* __restrict__ wih,
    const float* __restrict__ Wfhh, const float* __restrict__ Wbhh,
    const float* __restrict__ bf_ih, const float* __restrict__ bf_hh,
    const float* __restrict__ bb_ih, const float* __restrict__ bb_hh,
    const int* __restrict__ lengths, float* __restrict__ out,
    f16* __restrict__ xgring)
{
  const int tid = threadIdx.x;
  const int w   = tid >> 6;
  const int l   = tid & 63;
  const int sl  = (l & 3) | ((l >> 5) << 2);   // K-slice 0..7
  const int g   = w * 8 + ((l >> 2) & 7);      // row group
  const int r   = g * 8 + sl;                  // owned logical row 0..511
  const int uu  = r >> 2;
  const int gg  = r & 3;
  const int a_row = l & 15;                    // MFMA frag row / D col
  const int koff  = (l >> 4) * 8;              // MFMA frag k-offset
  const int dir = blockIdx.x >> 5;
  const int b   = blockIdx.x & 31;
  const float* Whh = dir ? Wbhh : Wfhh;
  const int L   = lengths[b];

  // W_hh rows for VALU dots (R11 layout)
  unsigned wrg[8][8];
  #pragma unroll
  for (int j = 0; j < 8; ++j) {
    int lrow = g * 8 + (j ^ sl);
    const float* src = &Whh[(size_t)((lrow & 3) * 128 + (lrow >> 2)) * H_ + sl * 16];
    #pragma unroll
    for (int k4 = 0; k4 < 4; ++k4) {
      float4 v = *(const float4*)&src[k4 * 4];
      wrg[j][2 * k4]     = __builtin_bit_cast(unsigned, (f16x2){ (f16)v.x, (f16)v.y });
      wrg[j][2 * k4 + 1] = __builtin_bit_cast(unsigned, (f16x2){ (f16)v.z, (f16)v.w });
    }
  }

  // biases for producer D columns (col = w*64+nt*16+a_row, unit-major)
  const float* bih_ = dir ? bb_ih : bf_ih;
  const float* bhh_ = dir ? bb_hh : bf_hh;
  float biasv[4];
  #pragma unroll
  for (int nt = 0; nt < 4; ++nt) {
    int ncol = w * 64 + nt * 16 + a_row;
    int grow = (ncol & 3) * 128 + (ncol >> 2);
    biasv[nt] = bih_[grow] + bhh_[grow];
  }

  __shared__ __align__(16) f16 xb[3][16][264];   // staged x (f16), 3 chunks
  __shared__ __align__(16) f16 hbuf[2][128];

  const size_t ringbase = (size_t)(dir * 32 + b) * 64 * 512;
  const f32x4 ZED = { 0.f, 0.f, 0.f, 0.f };

  auto stagex = [&](int chunk, int slot) {
    int xr = tid >> 5, c8 = (tid & 31) * 8;
    int t3 = chunk * CH_ + xr;
    int it3 = dir ? ((t3 < L) ? (L - 1 - t3) : t3) : t3;
    const float* xs_ = &x[(size_t)(b * T_ + it3) * I_ + c8];
    float4 va = *(const float4*)xs_;
    float4 vb = *(const float4*)(xs_ + 4);
    f16x8 hv = { (f16)va.x, (f16)va.y, (f16)va.z, (f16)va.w,
                 (f16)vb.x, (f16)vb.y, (f16)vb.z, (f16)vb.w };
    *(f16x8*)&xb[slot][xr][c8] = hv;
  };

  auto produce = [&](int chunk, int slot) {
    f32x4 e0, e1, e2, e3;
    #pragma unroll
    for (int kc = 0; kc < 8; ++kc) {
      f16x8 af = *(const f16x8*)&xb[slot][a_row][kc * 32 + koff];
      const f16* wb_ = wih + (size_t)(dir * 512 + w * 64 + a_row) * 256 + kc * 32 + koff;
      f16x8 q0 = *(const f16x8*)(wb_);
      f16x8 q1 = *(const f16x8*)(wb_ + 4096);
      f16x8 q2 = *(const f16x8*)(wb_ + 8192);
      f16x8 q3 = *(const f16x8*)(wb_ + 12288);
      if (kc == 0) { e0 = MFMA16(af, q0, ZED); e1 = MFMA16(af, q1, ZED);
                     e2 = MFMA16(af, q2, ZED); e3 = MFMA16(af, q3, ZED); }
      else         { e0 = MFMA16(af, q0, e0);  e1 = MFMA16(af, q1, e1);
                     e2 = MFMA16(af, q2, e2);  e3 = MFMA16(af, q3, e3);  }
    }
    #pragma unroll
    for (int i = 0; i < 16; ++i) {
      float val = ((i < 4) ? e0[i & 3] : (i < 8) ? e1[i & 3]
                  : (i < 12) ? e2[i & 3] : e3[i & 3]) + biasv[i >> 2];
      int s_out = (l >> 4) * 4 + (i & 3);
      int t_out = chunk * CH_ + s_out;
      int col   = w * 64 + (i >> 2) * 16 + a_row;
      xgring[ringbase + (size_t)(t_out & 63) * 512 + col] = (f16)val;
    }
  };

  // ---- prologue ----
  stagex(0, 0); stagex(1, 1); stagex(2, 2);
  __syncthreads();
  produce(0, 0); produce(1, 1);
  __builtin_amdgcn_sched_barrier(0);
  asm volatile("s_waitcnt vmcnt(0)" ::: "memory");
  __syncthreads();
  if (tid < 128) hbuf[0][tid] = (f16)0.0f;
  float c = 0.0f;
  __syncthreads();

  f16 pa = xgring[ringbase + 0 * 512 + r];
  f16 pb = xgring[ringbase + 1 * 512 + r];

  const float bscale = (gg == 2) ? 2.0f : 1.0f;
  const float bmul   = (gg == 2) ? 2.0f : 1.0f;
  const float badd   = (gg == 2) ? -1.0f : 0.0f;
  const bool  writer = (gg == 0);

#define STEPF(s, P)                                                          \
  {                                                                          \
    const int t = cc * CH_ + (s);                                            \
    float xv = (float)(P);                                                   \
    if (t + 2 < T_) P = xgring[ringbase + (size_t)((t + 2) & 63) * 512 + r]; \
    if (prod && (s) < 8) {                                                   \
      f16x8 af = *(const f16x8*)&xb[xread][a_row][(s) * 32 + koff];          \
      const f16* wb_ = wih + (size_t)(dir * 512 + w * 64 + a_row) * 256      \
                       + (s) * 32 + koff;                                    \
      f16x8 q0 = *(const f16x8*)(wb_);                                       \
      f16x8 q1 = *(const f16x8*)(wb_ + 4096);                                \
      f16x8 q2 = *(const f16x8*)(wb_ + 8192);                                \
      f16x8 q3 = *(const f16x8*)(wb_ + 12288);                               \
      if ((s) == 0) { d0 = MFMA16(af, q0, ZED); d1 = MFMA16(af, q1, ZED);    \
                      d2 = MFMA16(af, q2, ZED); d3 = MFMA16(af, q3, ZED); }  \
      else          { d0 = MFMA16(af, q0, d0);  d1 = MFMA16(af, q1, d1);     \
                      d2 = MFMA16(af, q2, d2);  d3 = MFMA16(af, q3, d3);  }  \
    }                                                                        \
    if (prod && (s) >= 8) {                                                  \
      _Pragma("unroll")                                                      \
      for (int e = 0; e < 2; ++e) {                                          \
        int i = ((s) - 8) * 2 + e;                                           \
        float val = ((i < 4) ? d0[i & 3] : (i < 8) ? d1[i & 3]               \
                    : (i < 12) ? d2[i & 3] : d3[i & 3]) + biasv[i >> 2];     \
        int s_out = (l >> 4) * 4 + (i & 3);                                  \
        int t_out = (cc + 2) * CH_ + s_out;                                  \
        int col   = w * 64 + (i >> 2) * 16 + a_row;                          \
        xgring[ringbase + (size_t)(t_out & 63) * 512 + col] = (f16)val;      \
      }                                                                      \
    }                                                                        \
    if (xload && (s) == 4) {                                                 \
      int xr = tid >> 5, c8 = (tid & 31) * 8;                                \
      int t3 = (cc + 3) * CH_ + xr;                                          \
      int it3 = dir ? ((t3 < L) ? (L - 1 - t3) : t3) : t3;                   \
      const float* xs_ = &x[(size_t)(b * T_ + it3) * I_ + c8];               \
      xva = *(const float4*)xs_;                                             \
      xvb = *(const float4*)(xs_ + 4);                                       \
    }                                                                        \
    if (xload && (s) == 14) {                                                \
      f16x8 hv = { (f16)xva.x, (f16)xva.y, (f16)xva.z, (f16)xva.w,           \
                   (f16)xvb.x, (f16)xvb.y, (f16)xvb.z, (f16)xvb.w };         \
      *(f16x8*)&xb[xwrit][tid >> 5][(tid & 31) * 8] = hv;                    \
    }                                                                        \
    uint4 hA = *(const uint4*)&hbuf[(s) & 1][sl * 16];                       \
    uint4 hB = *(const uint4*)&hbuf[(s) & 1][sl * 16 + 8];                   \
    float p[8] = { 0.f, 0.f, 0.f, 0.f, 0.f, 0.f, 0.f, 0.f };                 \
    _Pragma("unroll")                                                        \
    for (int j = 0; j < 8; ++j) {                                            \
      p[j] = FDOT2(asf16x2(hA.x), asf16x2(wrg[j][0]), p[j]);                 \
      p[j] = FDOT2(asf16x2(hA.y), asf16x2(wrg[j][1]), p[j]);                 \
      p[j] = FDOT2(asf16x2(hA.z), asf16x2(wrg[j][2]), p[j]);                 \
      p[j] = FDOT2(asf16x2(hA.w), asf16x2(wrg[j][3]), p[j]);                 \
      p[j] = FDOT2(asf16x2(hB.x), asf16x2(wrg[j][4]), p[j]);                 \
      p[j] = FDOT2(asf16x2(hB.y), asf16x2(wrg[j][5]), p[j]);                 \
      p[j] = FDOT2(asf16x2(hB.z), asf16x2(wrg[j][6]), p[j]);                 \
      p[j] = FDOT2(asf16x2(hB.w), asf16x2(wrg[j][7]), p[j]);                 \
    }                                                                        \
    p[0] += DPPF(p[1], 0xB1);                                                \
    p[2] += DPPF(p[3], 0xB1);                                                \
    p[4] += DPPF(p[5], 0xB1);                                                \
    p[6] += DPPF(p[7], 0xB1);                                                \
    p[0] += DPPF(p[2], 0x4E);                                                \
    p[4] += DPPF(p[6], 0x4E);                                                \
    p[0] += __shfl_xor(p[4], 32, 64);                                        \
    float sum = p[0] + xv;                                                   \
    float act = fast_sig(bscale * sum) * bmul + badd;                        \
    float a1 = DPPF(act, 0xB1);                                              \
    float a2 = DPPF(act, 0x4E);                                              \
    float a3 = DPPF(act, 0x1B);                                              \
    c = a1 * c + act * a2;                                                   \
    float hval = a3 * fast_tanh(c);                                          \
    if (writer) {                                                            \
      hbuf[((s) & 1) ^ 1][uu] = (f16)hval;                                   \
      out[(size_t)(b * T_ + t) * 256 + dir * 128 + uu] = hval;               \
    }                                                                        \
    BARRIER_LDS();                                                           \
  }

  for (int cc = 0; cc < NCH; ++cc) {
    const int  xread = (cc + 2) % 3;
    const int  xwrit = (cc + 3) % 3;
    const bool prod  = (cc + 2) < NCH;
    const bool xload = (cc + 3) < NCH;
    f32x4 d0, d1, d2, d3;
    float4 xva, xvb;

    #pragma unroll
    for (int s = 0; s < CH_; s += 2) {
      STEPF(s,     pa)
      STEPF(s + 1, pb)
    }

    if (prod) {   // publish ring stores before the chunk that prefetches them
      __builtin_amdgcn_sched_barrier(0);
      asm volatile("s_waitcnt vmcnt(0)" ::: "memory");
      __builtin_amdgcn_s_barrier();
      __builtin_amdgcn_sched_barrier(0);
    }
  }
#undef STEPF
}

// ---------------------------------------------------------------------------
extern "C" void kernel_launch(void* const* d_in, const int* in_sizes, int n_in,
                              void* d_out, int out_size, void* d_ws, size_t ws_size,
                              hipStream_t stream) {
  const float* x      = (const float*)d_in[0];
  const int*   lengths= (const int*)  d_in[1];
  const float* Wf_ih  = (const float*)d_in[2];
  const float* Wf_hh  = (const float*)d_in[3];
  const float* bf_ih  = (const float*)d_in[4];
  const float* bf_hh  = (const float*)d_in[5];
  const float* Wb_ih  = (const float*)d_in[6];
  const float* Wb_hh  = (const float*)d_in[7];
  const float* bb_ih  = (const float*)d_in[8];
  const float* bb_hh  = (const float*)d_in[9];
  float* out = (float*)d_out;

  f16* wih16  = (f16*)d_ws;                         // 2*512*256*2 = 512 KB
  f16* xgring = (f16*)d_ws + 2 * 512 * 256;         // 64*64*512*2 = 4 MB

  (void)in_sizes; (void)n_in; (void)out_size; (void)ws_size;

  wprep<<<dim3(1024), 64, 0, stream>>>(Wf_ih, Wb_ih, wih16);
  birnn_fused<<<dim3(64), 512, 0, stream>>>(x, wih16, Wf_hh, Wb_hh,
                                            bf_ih, bf_hh, bb_ih, bb_hh,
                                            lengths, out, xgring);
}

// Round 15
// 1104.899 us; speedup vs baseline: 1.7327x; 1.7327x over previous
//
#include <hip/hip_runtime.h>
#include <hip/hip_fp16.h>

#define B_  32
#define T_  2048
#define I_  256
#define H_  128

typedef _Float16 f16;
typedef _Float16 f16x2 __attribute__((ext_vector_type(2)));
typedef _Float16 f16x4 __attribute__((ext_vector_type(4)));
typedef _Float16 f16x8 __attribute__((ext_vector_type(8)));
typedef float    f32x4 __attribute__((ext_vector_type(4)));

#if __has_builtin(__builtin_amdgcn_fdot2)
#define FDOT2(a, b, c) __builtin_amdgcn_fdot2((a), (b), (c), false)
#else
static __device__ __forceinline__ float FDOT2(f16x2 a, f16x2 b, float c) {
  return c + (float)a[0] * (float)b[0] + (float)a[1] * (float)b[1];
}
#endif

static __device__ __forceinline__ f16x2 asf16x2(unsigned u) {
  return __builtin_bit_cast(f16x2, u);
}

// Cross-lane via DPP (VALU pipe -- NOT the DS pipe like shfl/bpermute)
//   quad_perm xor1: [1,0,3,2]=0xB1   xor2: [2,3,0,1]=0x4E   xor3: [3,2,1,0]=0x1B
//   row_ror:8 = 0x128 : within each 16-lane row, lane i reads (i+8)%16 == i^8
#define DPPF(x, ctrl)                                                      \
  __builtin_bit_cast(float, __builtin_amdgcn_mov_dpp(                      \
      __builtin_bit_cast(int, (x)), (ctrl), 0xF, 0xF, true))

static __device__ __forceinline__ float fast_sig(float x) {
  float e = __builtin_amdgcn_exp2f(-1.44269504089f * x);
  return __builtin_amdgcn_rcpf(1.0f + e);
}
static __device__ __forceinline__ float fast_tanh(float x) {
  float e = __builtin_amdgcn_exp2f(-2.88539008178f * x);
  return 2.0f * __builtin_amdgcn_rcpf(1.0f + e) - 1.0f;
}

// LDS-only barrier (no vmcnt drain).  sched_barrier fences per rule #18.
#define BARRIER_LDS()                                   \
  __builtin_amdgcn_sched_barrier(0);                    \
  asm volatile("s_waitcnt lgkmcnt(0)" ::: "memory");    \
  __builtin_amdgcn_s_barrier();                         \
  __builtin_amdgcn_sched_barrier(0)

#define MFMA16(a, b, c) __builtin_amdgcn_mfma_f32_16x16x32_f16((a), (b), (c), 0, 0, 0)

// ---------------------------------------------------------------------------
// Kernel 1: xg[m][col], col = dir*512 + unit*4 + gate  (gate 0=i 1=f 2=g 3=o)
//   value = x[m]·W_ih[grow] + b_ih[grow] + b_hh[grow], grow = gate*128+unit.
//   XCD-aware 1-D grid: xcd = bid&7 owns M-tiles [xcd*64, xcd*64+64) x all 8
//   N-tiles consecutively -> each x-tile is fetched into exactly ONE XCD L2
//   (was: 8 XCDs x 64MB = 512MB x-refetch).
// ---------------------------------------------------------------------------
__global__ __launch_bounds__(256) void xg_gemm(
    const float* __restrict__ x,
    const float* __restrict__ Wf, const float* __restrict__ Wb,
    const float* __restrict__ bf_ih, const float* __restrict__ bf_hh,
    const float* __restrict__ bb_ih, const float* __restrict__ bb_hh,
    f16* __restrict__ xg)
{
  __shared__ f16 xs[128][136];   // +8 f16 pad
  __shared__ f16 wt[128][136];

  const int tid  = threadIdx.x;
  const int bid  = blockIdx.x;          // 0..4095
  const int xcd  = bid & 7;
  const int slot = bid >> 3;            // 0..511
  const int m0   = (xcd * 64 + (slot >> 3)) * 128;
  const int n0   = (slot & 7) * 128;

  const float* Wsrc; const float* bih; const float* bhh; int nb; size_t dbase;
  if (n0 < 512) { Wsrc = Wf; bih = bf_ih; bhh = bf_hh; nb = n0;       dbase = 0; }
  else          { Wsrc = Wb; bih = bb_ih; bhh = bb_hh; nb = n0 - 512; dbase = 512; }

  const int w  = tid >> 6;
  const int l  = tid & 63;
  const int lr = l & 15;
  const int lk = (l >> 4) * 8;

  f32x4 acc[2][8] = {};

  #pragma unroll
  for (int kh = 0; kh < 2; ++kh) {
    #pragma unroll
    for (int it = 0; it < 16; ++it) {
      int idx = it * 256 + tid;
      int row = idx >> 5, c4 = idx & 31;
      float4 v = *(const float4*)&x[(size_t)(m0 + row) * I_ + kh * 128 + c4 * 4];
      f16x4 h4 = { (f16)v.x, (f16)v.y, (f16)v.z, (f16)v.w };
      *(f16x4*)&xs[row][c4 * 4] = h4;
    }
    #pragma unroll
    for (int it = 0; it < 16; ++it) {
      int idx = it * 256 + tid;
      int row = idx >> 5, c4 = idx & 31;
      float4 v = *(const float4*)&Wsrc[(size_t)(nb + row) * I_ + kh * 128 + c4 * 4];
      f16x4 h4 = { (f16)v.x, (f16)v.y, (f16)v.z, (f16)v.w };
      *(f16x4*)&wt[row][c4 * 4] = h4;
    }
    __syncthreads();

    #pragma unroll
    for (int ks = 0; ks < 4; ++ks) {
      int kk = ks * 32 + lk;
      f16x8 a0 = *(const f16x8*)&xs[w * 32 + lr][kk];
      f16x8 a1 = *(const f16x8*)&xs[w * 32 + 16 + lr][kk];
      #pragma unroll
      for (int nt = 0; nt < 8; ++nt) {
        f16x8 bf = *(const f16x8*)&wt[nt * 16 + lr][kk];
        acc[0][nt] = MFMA16(a0, bf, acc[0][nt]);
        acc[1][nt] = MFMA16(a1, bf, acc[1][nt]);
      }
    }
    __syncthreads();
  }

  // epilogue: D row = (l>>4)*4 + r, col = l&15; scatter to unit-major layout
  #pragma unroll
  for (int mt = 0; mt < 2; ++mt) {
    #pragma unroll
    for (int nt = 0; nt < 8; ++nt) {
      int nloc = nt * 16 + lr;
      int grow = nb + nloc;                 // gate-row within dir, 0..511
      int gate = grow >> 7, unit = grow & 127;
      size_t col = dbase + (size_t)unit * 4 + gate;
      float bias = bih[grow] + bhh[grow];
      #pragma unroll
      for (int r = 0; r < 4; ++r) {
        int m = m0 + w * 32 + mt * 16 + (l >> 4) * 4 + r;
        xg[(size_t)m * 1024 + col] = (f16)(acc[mt][nt][r] + bias);
      }
    }
  }
}

// ---------------------------------------------------------------------------
// Kernel 2: recurrence -- R11 structure with a FULLY DPP cross-lane network
//   (zero DS-pipe shuffles; the K-reduce's last level was a ds_bpermute).
//   64 WGs x 512 thr (8 waves).  Lane l of wave w:
//     sl = (l&3) | ((l>>3&1)<<2)            K-slice, lane bits {0,1,3}
//     g  = w*8 + ((l>>2)&1) + ((l>>4)&3)*2  row group,  lane bits {2,4,5}
//     owns rows g*8+(j^sl), j=0..7; owned row r = g*8+sl = unit*4+gate
//   K-reduce levels = sl bits: xor1 (quad 0xB1), xor2 (quad 0x4E),
//   xor-bit3 (row_ror:8 = 0x128) -- all VALU-pipe DPP.
//   Gate gather: unit's i,f,g,o live in the lane QUAD -> 0xB1/0x4E/0x1B.
//   DS ops/thread/step: 2 ds_read_b128 (+1 ds_write for writers).  ONE
//   LDS-only barrier per step; depth-2 global xg prefetch.
// ---------------------------------------------------------------------------
__global__ __launch_bounds__(512, 1) void birnn_rec(
    const f16* __restrict__ xg,
    const float* __restrict__ Wfhh, const float* __restrict__ Wbhh,
    const int* __restrict__ lengths,
    float* __restrict__ out)
{
  const int tid = threadIdx.x;
  const int w   = tid >> 6;
  const int l   = tid & 63;
  const int sl  = (l & 3) | (((l >> 3) & 1) << 2);           // K-slice 0..7
  const int g   = w * 8 + (((l >> 2) & 1) | (((l >> 4) & 3) << 1));
  const int r   = g * 8 + sl;                                // owned row 0..511
  const int uu  = r >> 2;                                    // unit 0..127
  const int gg  = r & 3;                                     // gate (== l&3)
  const int dir = blockIdx.x >> 5;
  const int b   = blockIdx.x & 31;
  const float* Whh = dir ? Wbhh : Wfhh;
  const int L   = lengths[b];

  // wrg[j][k]: logical row g*8+(j^sl), cols sl*16 + 2k..2k+1
  unsigned wrg[8][8];
  #pragma unroll
  for (int j = 0; j < 8; ++j) {
    int lrow = g * 8 + (j ^ sl);
    const float* src = &Whh[(size_t)((lrow & 3) * 128 + (lrow >> 2)) * H_ + sl * 16];
    #pragma unroll
    for (int k4 = 0; k4 < 4; ++k4) {
      float4 v = *(const float4*)&src[k4 * 4];
      wrg[j][2 * k4]     = __builtin_bit_cast(unsigned, (f16x2){ (f16)v.x, (f16)v.y });
      wrg[j][2 * k4 + 1] = __builtin_bit_cast(unsigned, (f16x2){ (f16)v.z, (f16)v.w });
    }
  }

  __shared__ __align__(16) f16 hbuf[2][128];
  if (tid < 128) hbuf[0][tid] = (f16)0.0f;
  float c = 0.0f;
  __syncthreads();

  auto rowof = [&](int t) -> size_t {
    int it = t;
    if (dir) it = (t < L) ? (L - 1 - t) : t;
    return (size_t)(b * T_ + it) * 1024 + (size_t)dir * 512 + (size_t)r;
  };

  // depth-2 xg prefetch (named slots)
  f16 pa = xg[rowof(0)];
  f16 pb = xg[rowof(1)];

  const float bscale = (gg == 2) ? 2.0f : 1.0f;   // gate g -> tanh = 2*sig(2x)-1
  const float bmul   = (gg == 2) ? 2.0f : 1.0f;
  const float badd   = (gg == 2) ? -1.0f : 0.0f;
  const bool  writer = (gg == 0);

#define STEP(t, P, RB, WB)                                                   \
  {                                                                          \
    float xv = (float)(P);                                                   \
    if ((t) + 2 < T_) P = xg[rowof((t) + 2)];                                \
    uint4 hA = *(const uint4*)&hbuf[RB][sl * 16];                            \
    uint4 hB = *(const uint4*)&hbuf[RB][sl * 16 + 8];                        \
    float p[8] = { 0.f, 0.f, 0.f, 0.f, 0.f, 0.f, 0.f, 0.f };                 \
    _Pragma("unroll")                                                        \
    for (int j = 0; j < 8; ++j) {                                            \
      p[j] = FDOT2(asf16x2(hA.x), asf16x2(wrg[j][0]), p[j]);                 \
      p[j] = FDOT2(asf16x2(hA.y), asf16x2(wrg[j][1]), p[j]);                 \
      p[j] = FDOT2(asf16x2(hA.z), asf16x2(wrg[j][2]), p[j]);                 \
      p[j] = FDOT2(asf16x2(hA.w), asf16x2(wrg[j][3]), p[j]);                 \
      p[j] = FDOT2(asf16x2(hB.x), asf16x2(wrg[j][4]), p[j]);                 \
      p[j] = FDOT2(asf16x2(hB.y), asf16x2(wrg[j][5]), p[j]);                 \
      p[j] = FDOT2(asf16x2(hB.z), asf16x2(wrg[j][6]), p[j]);                 \
      p[j] = FDOT2(asf16x2(hB.w), asf16x2(wrg[j][7]), p[j]);                 \
    }                                                                        \
    /* K-reduce: sl bits {0,1} quad_perm, bit {2}=lane-bit3 row_ror:8 */     \
    p[0] += DPPF(p[1], 0xB1);                                                \
    p[2] += DPPF(p[3], 0xB1);                                                \
    p[4] += DPPF(p[5], 0xB1);                                                \
    p[6] += DPPF(p[7], 0xB1);                                                \
    p[0] += DPPF(p[2], 0x4E);                                                \
    p[4] += DPPF(p[6], 0x4E);                                                \
    p[0] += DPPF(p[4], 0x128);                                               \
    float sum = p[0] + xv;                                                   \
    float act = fast_sig(bscale * sum) * bmul + badd;                        \
    /* gate gather within the lane quad (unit's i,f,g,o) -- pure DPP */      \
    float a1 = DPPF(act, 0xB1);                                              \
    float a2 = DPPF(act, 0x4E);                                              \
    float a3 = DPPF(act, 0x1B);                                              \
    /* gate-0 lanes: act=i, a1=f, a2=g, a3=o; others compute garbage */      \
    c = a1 * c + act * a2;                                                   \
    float hval = a3 * fast_tanh(c);                                          \
    if (writer) {                                                            \
      hbuf[WB][uu] = (f16)hval;                                              \
      out[(size_t)(b * T_ + (t)) * 256 + dir * 128 + uu] = hval;             \
    }                                                                        \
    BARRIER_LDS();                                                           \
  }

  for (int tt = 0; tt < T_; tt += 2) {
    STEP(tt,     pa, 0, 1)
    STEP(tt + 1, pb, 1, 0)
  }
#undef STEP
}

// ---------------------------------------------------------------------------
extern "C" void kernel_launch(void* const* d_in, const int* in_sizes, int n_in,
                              void* d_out, int out_size, void* d_ws, size_t ws_size,
                              hipStream_t stream) {
  const float* x      = (const float*)d_in[0];
  const int*   lengths= (const int*)  d_in[1];
  const float* Wf_ih  = (const float*)d_in[2];
  const float* Wf_hh  = (const float*)d_in[3];
  const float* bf_ih  = (const float*)d_in[4];
  const float* bf_hh  = (const float*)d_in[5];
  const float* Wb_ih  = (const float*)d_in[6];
  const float* Wb_hh  = (const float*)d_in[7];
  const float* bb_ih  = (const float*)d_in[8];
  const float* bb_hh  = (const float*)d_in[9];
  float* out = (float*)d_out;
  f16*   xg  = (f16*)d_ws;   // needs B*T*1024*2 = 134,217,728 bytes

  (void)in_sizes; (void)n_in; (void)out_size; (void)ws_size;

  xg_gemm<<<dim3(4096), 256, 0, stream>>>(x, Wf_ih, Wb_ih,
                                          bf_ih, bf_hh, bb_ih, bb_hh, xg);
  birnn_rec<<<dim3(64), 512, 0, stream>>>(xg, Wf_hh, Wb_hh, lengths, out);
}